// Round 3
// baseline (550.019 us; speedup 1.0000x reference)
//
#include <hip/hip_runtime.h>
#include <cstdint>
#include <cstddef>

// Problem constants
#define B_ROWS 16384
#define FEAT   2048
#define FIELD  32
#define KDIM   64
#define NCOLS  2048           // FIELD*KDIM (main quadratic columns)
#define NAUG   2176           // 2048 + 64 (vsum) + 1 (w) + 63 zero-pad = 17*128

using half8   = __attribute__((ext_vector_type(8))) _Float16;
using half4   = __attribute__((ext_vector_type(4))) _Float16;
using floatx4 = __attribute__((ext_vector_type(4))) float;

// Async global->LDS, 16B per lane. LDS dest must be wave-uniform base + lane*16.
__device__ __forceinline__ void load_lds16(const void* g, void* l) {
  __builtin_amdgcn_global_load_lds((const __attribute__((address_space(1))) void*)g,
                                   (__attribute__((address_space(3))) void*)l, 16, 0, 0);
}

// --- x fp32 -> fp16 (8 floats/thread, 16B store) ---------------------------
__global__ __launch_bounds__(256) void k_cvt_x(const float* __restrict__ x,
                                               _Float16* __restrict__ xh) {
  size_t i = (size_t)(blockIdx.x * 256 + threadIdx.x) * 8;  // 16384 blocks
  float4 v0 = *(const float4*)(x + i);
  float4 v1 = *(const float4*)(x + i + 4);
  half8 h = { (_Float16)v0.x, (_Float16)v0.y, (_Float16)v0.z, (_Float16)v0.w,
              (_Float16)v1.x, (_Float16)v1.y, (_Float16)v1.z, (_Float16)v1.w };
  *(half8*)(xh + i) = h;
}

// --- fused prep: vt transpose (blocks 0..1023), vsum rows (1024..1535),
//     w row + zero rows (1536..2047) --------------------------------------
__global__ __launch_bounds__(256) void k_prep(const float* __restrict__ v,
                                              const float* __restrict__ w,
                                              _Float16* __restrict__ vt) {
  const int bb = blockIdx.x;
  const int t = threadIdx.x;
  if (bb < 1024) {
    // v[f][n] fp32 -> vt[n][f] fp16 (64x64 tile transpose)
    __shared__ _Float16 tile[64 * 68];
    const int f0 = (bb >> 5) * 64;
    const int n0 = (bb & 31) * 64;
#pragma unroll
    for (int j = 0; j < 4; ++j) {
      int c = j * 256 + t;
      int row = c >> 4;                           // f local
      int col = (c & 15) * 4;                     // n local
      float4 val = *(const float4*)(v + (size_t)(f0 + row) * NCOLS + n0 + col);
      tile[row * 68 + col + 0] = (_Float16)val.x;
      tile[row * 68 + col + 1] = (_Float16)val.y;
      tile[row * 68 + col + 2] = (_Float16)val.z;
      tile[row * 68 + col + 3] = (_Float16)val.w;
    }
    __syncthreads();
#pragma unroll
    for (int j = 0; j < 4; ++j) {
      int c = j * 256 + t;
      int nl = c >> 4;                            // n local (row of vt)
      int fl = (c & 15) * 4;                      // f local group of 4
      half4 h = { tile[(fl + 0) * 68 + nl], tile[(fl + 1) * 68 + nl],
                  tile[(fl + 2) * 68 + nl], tile[(fl + 3) * 68 + nl] };
      *(half4*)(vt + (size_t)(n0 + nl) * FEAT + f0 + fl) = h;
    }
  } else if (bb < 1536) {
    // vsum rows: vt[2048+k][f] = sum_s v[f][s*64+k]
    const int k = t & 63;
    const int f = (bb - 1024) * 4 + (t >> 6);
    float s = 0.f;
#pragma unroll
    for (int si = 0; si < FIELD; ++si) s += v[(size_t)f * NCOLS + si * KDIM + k];
    vt[(size_t)(NCOLS + k) * FEAT + f] = (_Float16)s;
  } else {
    // w row (2112) + zero rows (2113..2175)
    int idx = (bb - 1536) * 256 + t;              // 64*2048 elements
    int r = NCOLS + KDIM + (idx >> 11);           // 2112..2175
    int f = idx & 2047;
    vt[(size_t)r * FEAT + f] = (r == NCOLS + KDIM) ? (_Float16)w[f] : (_Float16)0.f;
  }
}

// --- fused GEMM + row-reduce epilogue --------------------------------------
// C = xh[16384x2048] * vt^T (vt is [n][k], k contiguous). Per row m:
//   arg[m] += sum_n coeff(n, C[m,n]);  coeff: n<2048 -> -0.5*c^2,
//   2048<=n<2112 -> +0.5*c^2, n==2112 -> +c, else 0.
// A (xh) staged via global_load_lds (16 KB); B (vt, 8.9 MB total) fragments
// loaded DIRECTLY from global — issued before the barrier so they drain
// concurrently with A staging. Grid x-fast=m so co-resident blocks share one
// 0.5 MB B panel (L2-hot) and each A panel streams once per n-sweep.
__global__ __launch_bounds__(256) void k_gemm(const _Float16* __restrict__ xh,
                                              const _Float16* __restrict__ vt,
                                              float* __restrict__ arg) {
  __shared__ __align__(16) _Float16 lds_a[128 * 64];
  const int t = threadIdx.x;
  const int m0 = blockIdx.x * 128;
  const int n0 = blockIdx.y * 128;
  const int lane = t & 63;
  const int wave = t >> 6;
  const int wm = (wave & 1) * 64;
  const int wn = (wave >> 1) * 64;
  const int lr = lane & 15;                     // frag row (A) / col (B)
  const int lk = (lane >> 4) * 8;               // frag k offset

  floatx4 acc[4][4] = {};

  for (int k0 = 0; k0 < FEAT; k0 += 64) {
    // Stage A tile (128x64 fp16 = 16 KB): 1024 chunks of 16B.
    // XOR swizzle: row m, LDS slot j holds global k-chunk (j ^ (m&7)).
#pragma unroll
    for (int i = 0; i < 4; ++i) {
      int c = i * 256 + t;
      int row = c >> 3;
      int g = (c & 7) ^ (row & 7);              // global k-chunk index
      load_lds16(xh + (size_t)(m0 + row) * FEAT + k0 + g * 8, lds_a + c * 8);
    }
    // B fragments direct from global (drains alongside A staging at barrier).
    half8 bf[2][4];
#pragma unroll
    for (int ks = 0; ks < 2; ++ks)
#pragma unroll
      for (int f = 0; f < 4; ++f)
        bf[ks][f] = *(const half8*)(vt + (size_t)(n0 + wn + f * 16 + lr) * FEAT
                                    + k0 + ks * 32 + lk);
    __syncthreads();
#pragma unroll
    for (int ks = 0; ks < 2; ++ks) {
      const int kc = (ks * 32 + lk) >> 3;       // k-chunk 0..7
      half8 af[4];
#pragma unroll
      for (int f = 0; f < 4; ++f) {
        int ma = wm + f * 16 + lr;
        af[f] = *(const half8*)(lds_a + ma * 64 + (kc ^ (ma & 7)) * 8);
      }
#pragma unroll
      for (int fm = 0; fm < 4; ++fm)
#pragma unroll
        for (int fn = 0; fn < 4; ++fn)
          acc[fm][fn] = __builtin_amdgcn_mfma_f32_16x16x32_f16(af[fm], bf[ks][fn],
                                                               acc[fm][fn], 0, 0, 0);
    }
    __syncthreads();
  }

  // Epilogue: C/D layout col=lane&15, row=(lane>>4)*4+reg.
  const int cq = lane >> 4;
#pragma unroll
  for (int fm = 0; fm < 4; ++fm) {
#pragma unroll
    for (int r = 0; r < 4; ++r) {
      float contrib = 0.f;
#pragma unroll
      for (int fn = 0; fn < 4; ++fn) {
        int col = n0 + wn + fn * 16 + lr;
        float vv = acc[fm][fn][r];
        float q = vv * vv;
        if (col < NCOLS)                contrib -= 0.5f * q;
        else if (col < NCOLS + KDIM)    contrib += 0.5f * q;
        else if (col == NCOLS + KDIM)   contrib += vv;
      }
      contrib += __shfl_xor(contrib, 1);
      contrib += __shfl_xor(contrib, 2);
      contrib += __shfl_xor(contrib, 4);
      contrib += __shfl_xor(contrib, 8);
      if (lr == 0) atomicAdd(&arg[m0 + wm + fm * 16 + cq * 4 + r], contrib);
    }
  }
}

// --- finalize: sigmoid ------------------------------------------------------
__global__ __launch_bounds__(256) void k_fin(const float* __restrict__ arg,
                                             const float* __restrict__ b,
                                             float* __restrict__ out) {
  int i = blockIdx.x * 256 + threadIdx.x;
  float z = arg[i] + b[0];
  out[i] = 1.f / (1.f + __expf(-z));
}

extern "C" void kernel_launch(void* const* d_in, const int* in_sizes, int n_in,
                              void* d_out, int out_size, void* d_ws, size_t ws_size,
                              hipStream_t stream) {
  const float* x = (const float*)d_in[0];   // [16384, 2048]
  const float* w = (const float*)d_in[1];   // [2048]
  const float* b = (const float*)d_in[2];   // scalar
  const float* v = (const float*)d_in[3];   // [2048, 32, 64]
  float* out = (float*)d_out;               // [16384] fp32

  char* ws = (char*)d_ws;
  _Float16* xh  = (_Float16*)ws;                          // 67,108,864 B
  _Float16* vt  = (_Float16*)(ws + 67108864);             //  8,912,896 B
  float*    arg = (float*)(ws + 67108864 + 8912896);      //     65,536 B

  hipMemsetAsync(arg, 0, B_ROWS * sizeof(float), stream);
  k_cvt_x<<<16384, 256, 0, stream>>>(x, xh);
  k_prep<<<2048, 256, 0, stream>>>(v, w, vt);
  k_gemm<<<dim3(128, 17), 256, 0, stream>>>(xh, vt, arg);
  k_fin<<<64, 256, 0, stream>>>(arg, b, out);
}

// Round 4
// 409.580 us; speedup vs baseline: 1.3429x; 1.3429x over previous
//
#include <hip/hip_runtime.h>
#include <cstdint>
#include <cstddef>

// Problem constants
#define B_ROWS 16384
#define FEAT   2048
#define FIELD  32
#define KDIM   64
#define NCOLS  2048           // FIELD*KDIM (main quadratic columns)
#define NAUG   2176           // 2048 + 64 (vsum) + 1 (w) + 63 zero-pad = 17*128

using half8   = __attribute__((ext_vector_type(8))) _Float16;
using half4   = __attribute__((ext_vector_type(4))) _Float16;
using floatx4 = __attribute__((ext_vector_type(4))) float;

// Async global->LDS, 16B per lane. LDS dest must be wave-uniform base + lane*16.
__device__ __forceinline__ void load_lds16(const void* g, void* l) {
  __builtin_amdgcn_global_load_lds((const __attribute__((address_space(1))) void*)g,
                                   (__attribute__((address_space(3))) void*)l, 16, 0, 0);
}

// --- fused prep: one launch does everything the gemm needs -----------------
// blocks [0,8192):      x fp32 -> xh fp16, 16 floats/thread
// blocks [8192,9216):   v[f][n] -> vt[n][f] fp16 transpose (64x64 tiles)
// blocks [9216,9728):   vsum rows vt[2048+k][f] = sum_s v[f][s*64+k]
// blocks [9728,10240):  w row (2112) + zero rows (2113..2175)
// blocks [10240,10304): zero arg[16384]
__global__ __launch_bounds__(256) void k_prep(const float* __restrict__ x,
                                              const float* __restrict__ v,
                                              const float* __restrict__ w,
                                              _Float16* __restrict__ xh,
                                              _Float16* __restrict__ vt,
                                              float* __restrict__ arg) {
  const int bb = blockIdx.x;
  const int t = threadIdx.x;
  if (bb < 8192) {
    size_t i = ((size_t)bb * 256 + t) * 16;
    float4 v0 = *(const float4*)(x + i);
    float4 v1 = *(const float4*)(x + i + 4);
    float4 v2 = *(const float4*)(x + i + 8);
    float4 v3 = *(const float4*)(x + i + 12);
    half8 h0 = { (_Float16)v0.x, (_Float16)v0.y, (_Float16)v0.z, (_Float16)v0.w,
                 (_Float16)v1.x, (_Float16)v1.y, (_Float16)v1.z, (_Float16)v1.w };
    half8 h1 = { (_Float16)v2.x, (_Float16)v2.y, (_Float16)v2.z, (_Float16)v2.w,
                 (_Float16)v3.x, (_Float16)v3.y, (_Float16)v3.z, (_Float16)v3.w };
    *(half8*)(xh + i) = h0;
    *(half8*)(xh + i + 8) = h1;
  } else if (bb < 9216) {
    __shared__ _Float16 tile[64 * 68];
    const int b2 = bb - 8192;
    const int f0 = (b2 >> 5) * 64;
    const int n0 = (b2 & 31) * 64;
#pragma unroll
    for (int j = 0; j < 4; ++j) {
      int c = j * 256 + t;
      int row = c >> 4;                           // f local
      int col = (c & 15) * 4;                     // n local
      float4 val = *(const float4*)(v + (size_t)(f0 + row) * NCOLS + n0 + col);
      tile[row * 68 + col + 0] = (_Float16)val.x;
      tile[row * 68 + col + 1] = (_Float16)val.y;
      tile[row * 68 + col + 2] = (_Float16)val.z;
      tile[row * 68 + col + 3] = (_Float16)val.w;
    }
    __syncthreads();
#pragma unroll
    for (int j = 0; j < 4; ++j) {
      int c = j * 256 + t;
      int nl = c >> 4;                            // n local (row of vt)
      int fl = (c & 15) * 4;                      // f local group of 4
      half4 h = { tile[(fl + 0) * 68 + nl], tile[(fl + 1) * 68 + nl],
                  tile[(fl + 2) * 68 + nl], tile[(fl + 3) * 68 + nl] };
      *(half4*)(vt + (size_t)(n0 + nl) * FEAT + f0 + fl) = h;
    }
  } else if (bb < 9728) {
    const int k = t & 63;
    const int f = (bb - 9216) * 4 + (t >> 6);
    float s = 0.f;
#pragma unroll
    for (int si = 0; si < FIELD; ++si) s += v[(size_t)f * NCOLS + si * KDIM + k];
    vt[(size_t)(NCOLS + k) * FEAT + f] = (_Float16)s;
  } else if (bb < 10240) {
    int idx = (bb - 9728) * 256 + t;              // 64*2048 elements
    int r = NCOLS + KDIM + (idx >> 11);           // 2112..2175
    int f = idx & 2047;
    vt[(size_t)r * FEAT + f] = (r == NCOLS + KDIM) ? (_Float16)w[f] : (_Float16)0.f;
  } else {
    arg[(bb - 10240) * 256 + t] = 0.f;
  }
}

// --- fused GEMM + row-reduce epilogue (R1 structure, known 220 us) ---------
// C = xh[16384x2048] * vt^T (vt is [n][k], k contiguous). Per row m:
//   arg[m] += sum_n coeff(n, C[m,n]);  coeff: n<2048 -> -0.5*c^2,
//   2048<=n<2112 -> +0.5*c^2, n==2112 -> +c, else 0.
// Grid x-fast=m: co-resident blocks share one B panel (L2-hot), A streamed.
__global__ __launch_bounds__(256) void k_gemm(const _Float16* __restrict__ xh,
                                              const _Float16* __restrict__ vt,
                                              float* __restrict__ arg) {
  __shared__ __align__(16) _Float16 lds_a[128 * 64];
  __shared__ __align__(16) _Float16 lds_b[128 * 64];
  const int t = threadIdx.x;
  const int m0 = blockIdx.x * 128;
  const int n0 = blockIdx.y * 128;
  const int lane = t & 63;
  const int wave = t >> 6;
  const int wm = (wave & 1) * 64;
  const int wn = (wave >> 1) * 64;
  const int lr = lane & 15;                     // frag row (A) / col (B)
  const int lk = (lane >> 4) * 8;               // frag k offset

  floatx4 acc[4][4] = {};

  for (int k0 = 0; k0 < FEAT; k0 += 64) {
    // Stage A,B tiles (128x64 fp16 each): 1024 chunks of 16B per tile.
    // XOR swizzle: row m, LDS slot j holds global k-chunk (j ^ (m&7)).
#pragma unroll
    for (int i = 0; i < 4; ++i) {
      int c = i * 256 + t;
      int row = c >> 3;
      int g = (c & 7) ^ (row & 7);              // global k-chunk index
      load_lds16(xh + (size_t)(m0 + row) * FEAT + k0 + g * 8, lds_a + c * 8);
      load_lds16(vt + (size_t)(n0 + row) * FEAT + k0 + g * 8, lds_b + c * 8);
    }
    __syncthreads();
#pragma unroll
    for (int ks = 0; ks < 64; ks += 32) {
      const int kc = (ks + lk) >> 3;            // k-chunk 0..7
      half8 af[4], bf[4];
#pragma unroll
      for (int f = 0; f < 4; ++f) {
        int ma = wm + f * 16 + lr;
        int nb = wn + f * 16 + lr;
        af[f] = *(const half8*)(lds_a + ma * 64 + (kc ^ (ma & 7)) * 8);
        bf[f] = *(const half8*)(lds_b + nb * 64 + (kc ^ (nb & 7)) * 8);
      }
#pragma unroll
      for (int fm = 0; fm < 4; ++fm)
#pragma unroll
        for (int fn = 0; fn < 4; ++fn)
          acc[fm][fn] = __builtin_amdgcn_mfma_f32_16x16x32_f16(af[fm], bf[fn],
                                                               acc[fm][fn], 0, 0, 0);
    }
    __syncthreads();
  }

  // Epilogue: C/D layout col=lane&15, row=(lane>>4)*4+reg.
  const int cq = lane >> 4;
#pragma unroll
  for (int fm = 0; fm < 4; ++fm) {
#pragma unroll
    for (int r = 0; r < 4; ++r) {
      float contrib = 0.f;
#pragma unroll
      for (int fn = 0; fn < 4; ++fn) {
        int col = n0 + wn + fn * 16 + lr;
        float vv = acc[fm][fn][r];
        float q = vv * vv;
        if (col < NCOLS)                contrib -= 0.5f * q;
        else if (col < NCOLS + KDIM)    contrib += 0.5f * q;
        else if (col == NCOLS + KDIM)   contrib += vv;
      }
      contrib += __shfl_xor(contrib, 1);
      contrib += __shfl_xor(contrib, 2);
      contrib += __shfl_xor(contrib, 4);
      contrib += __shfl_xor(contrib, 8);
      if (lr == 0) atomicAdd(&arg[m0 + wm + fm * 16 + cq * 4 + r], contrib);
    }
  }
}

// --- finalize: sigmoid ------------------------------------------------------
__global__ __launch_bounds__(256) void k_fin(const float* __restrict__ arg,
                                             const float* __restrict__ b,
                                             float* __restrict__ out) {
  int i = blockIdx.x * 256 + threadIdx.x;
  float z = arg[i] + b[0];
  out[i] = 1.f / (1.f + __expf(-z));
}

extern "C" void kernel_launch(void* const* d_in, const int* in_sizes, int n_in,
                              void* d_out, int out_size, void* d_ws, size_t ws_size,
                              hipStream_t stream) {
  const float* x = (const float*)d_in[0];   // [16384, 2048]
  const float* w = (const float*)d_in[1];   // [2048]
  const float* b = (const float*)d_in[2];   // scalar
  const float* v = (const float*)d_in[3];   // [2048, 32, 64]
  float* out = (float*)d_out;               // [16384] fp32

  char* ws = (char*)d_ws;
  _Float16* xh  = (_Float16*)ws;                          // 67,108,864 B
  _Float16* vt  = (_Float16*)(ws + 67108864);             //  8,912,896 B
  float*    arg = (float*)(ws + 67108864 + 8912896);      //     65,536 B

  k_prep<<<10304, 256, 0, stream>>>(x, v, w, xh, vt, arg);
  k_gemm<<<dim3(128, 17), 256, 0, stream>>>(xh, vt, arg);
  k_fin<<<64, 256, 0, stream>>>(arg, b, out);
}